// Round 2
// baseline (286.336 us; speedup 1.0000x reference)
//
#include <hip/hip_runtime.h>
#include <hip/hip_bf16.h>
#include <hip/hip_fp16.h>
#include <math.h>

typedef __hip_bfloat16 bf16;
#define NEG_SLOPE 0.2f
#define SFLAG (1 << 30)

typedef _Float16 f16x8 __attribute__((ext_vector_type(8)));
typedef float f32x4 __attribute__((ext_vector_type(4)));

// ====== dtype detect (block 0) + zero deg/scan-state =========================
__global__ void k_detect_zero(const unsigned short* __restrict__ x, int* __restrict__ flag,
                              int* __restrict__ zbase, int n) {
    for (int i = blockIdx.x * blockDim.x + threadIdx.x; i < n; i += gridDim.x * blockDim.x)
        zbase[i] = 0;
    if (blockIdx.x == 0) {
        __shared__ int cnt;
        if (threadIdx.x == 0) cnt = 0;
        __syncthreads();
        int local = 0;
        for (int i = threadIdx.x; i < 2048; i += blockDim.x) {
            unsigned short w = x[2 * i];
            int e = (w >> 7) & 0xFF;
            if (e >= 0x90) local++;
        }
        atomicAdd(&cnt, local);
        __syncthreads();
        if (threadIdx.x == 0) flag[0] = (cnt > 100) ? 1 : 0;  // 1 => inputs are f32
    }
}

#define NSEG 25
struct Seg { const void* src; int n; int off; };
struct Tab { Seg s[NSEG]; };

__device__ __forceinline__ float ldconv(const void* src, int i, int f32mode) {
    return f32mode ? ((const float*)src)[i]
                   : __bfloat162float(((const bf16*)src)[i]);
}

// ====== convert weights fp32 + transposed f16 weights + degree/rank ==========
__global__ void k_convert(Tab tab, float* __restrict__ dst, const int* __restrict__ flag,
                          const int* __restrict__ dstArr, int E, int N,
                          int* __restrict__ deg, int* __restrict__ rank,
                          const void* a2WlS, const void* a2WrS,
                          const void* gWlS, const void* gWrS,
                          __half* __restrict__ a2Wlt, __half* __restrict__ a2Wrt,
                          __half* __restrict__ gWlt, __half* __restrict__ gWrt) {
    int f32mode = flag[0];
    int gid = blockIdx.x * blockDim.x + threadIdx.x;
    int gsz = gridDim.x * blockDim.x;
    for (int s = 0; s < NSEG; s++) {
        Seg sg = tab.s[s];
        for (int i = gid; i < sg.n; i += gsz) {
            dst[sg.off + i] = ldconv(sg.src, i, f32mode);
        }
    }
    // transposed f16 weights: Wt[j][k] = W[k][j]
    for (int i = gid; i < 128 * 128; i += gsz) {
        int k = i >> 7, j = i & 127;
        a2Wlt[(size_t)j * 128 + k] = __float2half(ldconv(a2WlS, i, f32mode));
        a2Wrt[(size_t)j * 128 + k] = __float2half(ldconv(a2WrS, i, f32mode));
    }
    for (int i = gid; i < 128 * 32; i += gsz) {
        int k = i >> 5, j = i & 31;
        gWlt[(size_t)j * 128 + k] = __float2half(ldconv(gWlS, i, f32mode));
        gWrt[(size_t)j * 128 + k] = __float2half(ldconv(gWrS, i, f32mode));
    }
    int EA = E + N;
    for (int e = gid; e < EA; e += gsz) {
        int d = (e < E) ? dstArr[e] : (e - E);
        rank[e] = atomicAdd(&deg[d], 1);
    }
}

// ====== single-kernel chained-lookback exclusive scan ========================
__launch_bounds__(1024)
__global__ void k_scanf(const int* __restrict__ deg, int* __restrict__ offs,
                        int n, int* __restrict__ st, int nb) {
    __shared__ int ws[16];
    __shared__ int stot, sprev;
    int tile = blockIdx.x;
    int i = tile * 1024 + threadIdx.x;
    int lane = threadIdx.x & 63, wid = threadIdx.x >> 6;
    int v = (i < n) ? deg[i] : 0;
    int x = v;
    #pragma unroll
    for (int o = 1; o < 64; o <<= 1) {
        int y = __shfl_up(x, o);
        if (lane >= o) x += y;
    }
    if (lane == 63) ws[wid] = x;
    __syncthreads();
    if (wid == 0) {
        int w = (lane < 16) ? ws[lane] : 0;
        int s = w;
        #pragma unroll
        for (int o = 1; o < 16; o <<= 1) {
            int y = __shfl_up(s, o);
            if (lane >= o) s += y;
        }
        if (lane < 16) ws[lane] = s - w;
        if (lane == 15) stot = s;
    }
    __syncthreads();
    int local = ws[wid] + x - v;     // block-local exclusive
    if (threadIdx.x == 0) {
        int prev = 0;
        if (tile > 0) {
            int vv;
            while ((((vv = __hip_atomic_load(&st[tile - 1], __ATOMIC_ACQUIRE,
                                             __HIP_MEMORY_SCOPE_AGENT))) & SFLAG) == 0) {}
            prev = vv & ~SFLAG;
        }
        __hip_atomic_store(&st[tile], (prev + stot) | SFLAG, __ATOMIC_RELEASE,
                           __HIP_MEMORY_SCOPE_AGENT);
        sprev = prev;
        if (tile == nb - 1) offs[n] = prev + stot;
    }
    __syncthreads();
    if (i < n) offs[i] = sprev + local;
}

// ====== fused: CSR fill via rank (blocks >= EB) + embed+conv1-linear =========
__launch_bounds__(256)
__global__ void k_fill_embedlin(const int* __restrict__ srcArr, const int* __restrict__ dstArr,
                                int E, int N, const int* __restrict__ offs,
                                const int* __restrict__ rank, int* __restrict__ csr,
                                const void* __restrict__ xraw, const int* __restrict__ flag,
                                const float* __restrict__ aeW, const float* __restrict__ aeb,
                                const float* __restrict__ Wl, const float* __restrict__ bl,
                                const float* __restrict__ Wr, const float* __restrict__ br,
                                __half* __restrict__ outl, float* __restrict__ outr,
                                int EB) {
    __shared__ float xs[100 * 36];
    __shared__ float axs[32 * 36];
    if (blockIdx.x >= EB) {
        int e = (blockIdx.x - EB) * 256 + threadIdx.x;
        int EA = E + N;
        if (e >= EA) return;
        int d, s;
        if (e < E) { d = dstArr[e]; s = srcArr[e]; } else { d = s = e - E; }
        csr[offs[d] + rank[e]] = s;     // no atomics: rank captured during count
        return;
    }
    constexpr int NTP = 36;
    int t = threadIdx.x, nb = blockIdx.x * 32;
    if (flag[0]) {
        const float4* x4 = (const float4*)xraw;
        for (int idx = t; idx < 32 * 25; idx += 256) {
            int node = idx / 25, k4 = idx % 25;
            float4 v = x4[(size_t)(nb + node) * 25 + k4];
            xs[(k4 * 4 + 0) * NTP + node] = v.x;
            xs[(k4 * 4 + 1) * NTP + node] = v.y;
            xs[(k4 * 4 + 2) * NTP + node] = v.z;
            xs[(k4 * 4 + 3) * NTP + node] = v.w;
        }
    } else {
        const ushort4* xu = (const ushort4*)xraw;
        for (int idx = t; idx < 32 * 25; idx += 256) {
            int node = idx / 25, k4 = idx % 25;
            ushort4 u = xu[(size_t)(nb + node) * 25 + k4];
            xs[(k4 * 4 + 0) * NTP + node] = __uint_as_float((unsigned)u.x << 16);
            xs[(k4 * 4 + 1) * NTP + node] = __uint_as_float((unsigned)u.y << 16);
            xs[(k4 * 4 + 2) * NTP + node] = __uint_as_float((unsigned)u.z << 16);
            xs[(k4 * 4 + 3) * NTP + node] = __uint_as_float((unsigned)u.w << 16);
        }
    }
    __syncthreads();
    {
        int j = t & 31, g0 = t >> 5;
        float a0 = 0.f, a1 = 0.f, a2 = 0.f, a3 = 0.f;
        #pragma unroll 10
        for (int k = 0; k < 100; k++) {
            float w = aeW[k * 32 + j];
            const float4 xv = *(const float4*)&xs[k * NTP + g0 * 4];
            a0 += w * xv.x; a1 += w * xv.y; a2 += w * xv.z; a3 += w * xv.w;
        }
        float bj = aeb[j];
        axs[j * NTP + g0 * 4 + 0] = fmaxf(a0 + bj, 0.f);
        axs[j * NTP + g0 * 4 + 1] = fmaxf(a1 + bj, 0.f);
        axs[j * NTP + g0 * 4 + 2] = fmaxf(a2 + bj, 0.f);
        axs[j * NTP + g0 * 4 + 3] = fmaxf(a3 + bj, 0.f);
    }
    __syncthreads();
    {
        int j = t & 63, g0 = t >> 6;
        float aL0[2][4], aL1[2][4], aR0[2][4], aR1[2][4];
        #pragma unroll
        for (int g = 0; g < 2; g++)
            #pragma unroll
            for (int c = 0; c < 4; c++) { aL0[g][c]=0.f; aL1[g][c]=0.f; aR0[g][c]=0.f; aR1[g][c]=0.f; }
        #pragma unroll 4
        for (int k = 0; k < 32; k++) {
            float wl0 = Wl[k * 128 + j];
            float wl1 = Wl[k * 128 + j + 64];
            float wr0 = Wr[k * 128 + j];
            float wr1 = Wr[k * 128 + j + 64];
            #pragma unroll
            for (int g = 0; g < 2; g++) {
                const float4 xv = *(const float4*)&axs[k * NTP + (g0 + g * 4) * 4];
                aL0[g][0] += wl0 * xv.x; aL0[g][1] += wl0 * xv.y; aL0[g][2] += wl0 * xv.z; aL0[g][3] += wl0 * xv.w;
                aL1[g][0] += wl1 * xv.x; aL1[g][1] += wl1 * xv.y; aL1[g][2] += wl1 * xv.z; aL1[g][3] += wl1 * xv.w;
                aR0[g][0] += wr0 * xv.x; aR0[g][1] += wr0 * xv.y; aR0[g][2] += wr0 * xv.z; aR0[g][3] += wr0 * xv.w;
                aR1[g][0] += wr1 * xv.x; aR1[g][1] += wr1 * xv.y; aR1[g][2] += wr1 * xv.z; aR1[g][3] += wr1 * xv.w;
            }
        }
        float bl0 = bl[j], bl1 = bl[j + 64], br0 = br[j], br1 = br[j + 64];
        #pragma unroll
        for (int g = 0; g < 2; g++) {
            int n0 = nb + (g0 + g * 4) * 4;
            #pragma unroll
            for (int c = 0; c < 4; c++) {
                size_t row = (size_t)(n0 + c) * 128;
                outl[row + j]      = __float2half(aL0[g][c] + bl0);
                outl[row + j + 64] = __float2half(aL1[g][c] + bl1);
                outr[row + j]      = aR0[g][c] + br0;
                outr[row + j + 64] = aR1[g][c] + br1;
            }
        }
    }
}

// ====== per-edge math (16-lane group, 8 channels/lane) =======================
__device__ __forceinline__ void gat_proc(float4 raw, bool valid,
                                         const float* xrd, const float* av,
                                         float* acc, float& sm) {
    const __half2* h = (const __half2*)&raw;
    float v[8];
    float2 f;
    f = __half22float2(h[0]); v[0] = f.x; v[1] = f.y;
    f = __half22float2(h[1]); v[2] = f.x; v[3] = f.y;
    f = __half22float2(h[2]); v[4] = f.x; v[5] = f.y;
    f = __half22float2(h[3]); v[6] = f.x; v[7] = f.y;
    float p = 0.f;
    #pragma unroll
    for (int c = 0; c < 8; c++) {
        float u = v[c] + xrd[c];
        u = (u > 0.f) ? u : NEG_SLOPE * u;
        p += u * av[c];
    }
    p += __shfl_xor(p, 1);
    p += __shfl_xor(p, 2);
    p += __shfl_xor(p, 4);
    p += __shfl_xor(p, 8);
    float w = __expf(fminf(p, 80.f));
    if (!valid) w = 0.f;
    sm += w;
    #pragma unroll
    for (int c = 0; c < 8; c++) acc[c] += w * v[c];
}

// ====== GAT H=4 gather of a 32-dst tile into LDS (fp16, node-major) ==========
// Dual dst per 16-lane group: two independent gather chains interleaved
// -> 8 row-loads in flight per group (32/wave); A's stall overlaps B's
// compute. Half the blocks of the 16-dst tile (less launch/barrier cost).
// xsh layout: xsh[node * 136 + ch], node in [0,32), ch in [0,128). 8.7 KB.
__device__ __forceinline__ void gat32_to_lds(__half* xsh,
                                             const __half* __restrict__ xl,
                                             const float* __restrict__ xr,
                                             const float* __restrict__ att,
                                             const int* __restrict__ offs,
                                             const int* __restrict__ csr,
                                             const float* __restrict__ bias,
                                             int nb, int N) {
    int t = threadIdx.x;
    int wave = t >> 6, lane = t & 63;
    int grp = lane >> 4, sub = lane & 15;     // group owns two dsts
    int lb = lane & 48;                       // group base lane
    float av[8];
    {
        const float4* t4 = (const float4*)(att + sub * 8);
        float4 c = t4[0], e = t4[1];
        av[0]=c.x; av[1]=c.y; av[2]=c.z; av[3]=c.w;
        av[4]=e.x; av[5]=e.y; av[6]=e.z; av[7]=e.w;
    }
    int dA = nb + wave * 8 + grp * 2;
    int dB = dA + 1;
    bool okA = dA < N, okB = dB < N;
    int iA0 = okA ? offs[dA] : 0, iA1 = okA ? offs[dA + 1] : 0;
    int iB0 = okB ? offs[dB] : 0, iB1 = okB ? offs[dB + 1] : 0;
    int cntA = iA1 - iA0, cntB = iB1 - iB0;

    float xrdA[8], xrdB[8];
    #pragma unroll
    for (int c = 0; c < 8; c++) { xrdA[c] = 0.f; xrdB[c] = 0.f; }
    if (okA) {
        const float4* p4 = (const float4*)(xr + (size_t)dA * 128 + sub * 8);
        float4 a = p4[0], b = p4[1];
        xrdA[0]=a.x; xrdA[1]=a.y; xrdA[2]=a.z; xrdA[3]=a.w;
        xrdA[4]=b.x; xrdA[5]=b.y; xrdA[6]=b.z; xrdA[7]=b.w;
    }
    if (okB) {
        const float4* p4 = (const float4*)(xr + (size_t)dB * 128 + sub * 8);
        float4 a = p4[0], b = p4[1];
        xrdB[0]=a.x; xrdB[1]=a.y; xrdB[2]=a.z; xrdB[3]=a.w;
        xrdB[4]=b.x; xrdB[5]=b.y; xrdB[6]=b.z; xrdB[7]=b.w;
    }
    float accA[8], accB[8];
    #pragma unroll
    for (int c = 0; c < 8; c++) { accA[c] = 0.f; accB[c] = 0.f; }
    float smA = 0.f, smB = 0.f;

    // first csr chunks (one coalesced 64B load per group per dst)
    int myvA = (sub < cntA) ? csr[iA0 + sub] : 0;
    int myvB = (sub < cntB) ? csr[iB0 + sub] : 0;
    int nCh = max((cntA + 15) >> 4, (cntB + 15) >> 4);
    for (int ch = 0; ch < nCh; ch++) {
        int c0 = ch * 16;
        // prefetch next chunks' indices while processing current
        int nxtA = (c0 + 16 + sub < cntA) ? csr[iA0 + c0 + 16 + sub] : 0;
        int nxtB = (c0 + 16 + sub < cntB) ? csr[iB0 + c0 + 16 + sub] : 0;
        int remA = cntA - c0; if (remA > 16) remA = 16;
        int remB = cntB - c0; if (remB > 16) remB = 16;
        int remM = remA > remB ? remA : remB;
        for (int k = 0; k < remM; k += 4) {
            bool doA = k < remA, doB = k < remB;
            float4 rA0, rA1, rA2, rA3, rB0, rB1, rB2, rB3;
            if (doA) {
                int s0 = __shfl(myvA, lb + k + 0);
                int s1 = __shfl(myvA, lb + k + 1);
                int s2 = __shfl(myvA, lb + k + 2);
                int s3 = __shfl(myvA, lb + k + 3);
                rA0 = *(const float4*)(xl + (size_t)s0 * 128 + sub * 8);
                rA1 = *(const float4*)(xl + (size_t)s1 * 128 + sub * 8);
                rA2 = *(const float4*)(xl + (size_t)s2 * 128 + sub * 8);
                rA3 = *(const float4*)(xl + (size_t)s3 * 128 + sub * 8);
            }
            if (doB) {
                int s0 = __shfl(myvB, lb + k + 0);
                int s1 = __shfl(myvB, lb + k + 1);
                int s2 = __shfl(myvB, lb + k + 2);
                int s3 = __shfl(myvB, lb + k + 3);
                rB0 = *(const float4*)(xl + (size_t)s0 * 128 + sub * 8);
                rB1 = *(const float4*)(xl + (size_t)s1 * 128 + sub * 8);
                rB2 = *(const float4*)(xl + (size_t)s2 * 128 + sub * 8);
                rB3 = *(const float4*)(xl + (size_t)s3 * 128 + sub * 8);
            }
            if (doA) {
                gat_proc(rA0, true,         xrdA, av, accA, smA);
                gat_proc(rA1, k + 1 < remA, xrdA, av, accA, smA);
                gat_proc(rA2, k + 2 < remA, xrdA, av, accA, smA);
                gat_proc(rA3, k + 3 < remA, xrdA, av, accA, smA);
            }
            if (doB) {
                gat_proc(rB0, true,         xrdB, av, accB, smB);
                gat_proc(rB1, k + 1 < remB, xrdB, av, accB, smB);
                gat_proc(rB2, k + 2 < remB, xrdB, av, accB, smB);
                gat_proc(rB3, k + 3 < remB, xrdB, av, accB, smB);
            }
        }
        myvA = nxtA; myvB = nxtB;
    }

    // acc holds the full per-dst sum (group's 16 lanes cover 128 ch)
    if (okA) {
        float inv = 1.f / (smA + 1e-16f);
        int node = wave * 8 + grp * 2;
        int chb = sub * 8;
        #pragma unroll
        for (int c = 0; c < 8; c += 2) {
            __half2 hv;
            hv.x = __float2half(fmaxf(accA[c]     * inv + bias[chb + c],     0.f));
            hv.y = __float2half(fmaxf(accA[c + 1] * inv + bias[chb + c + 1], 0.f));
            *(__half2*)&xsh[node * 136 + chb + c] = hv;
        }
    }
    if (okB) {
        float inv = 1.f / (smB + 1e-16f);
        int node = wave * 8 + grp * 2 + 1;
        int chb = sub * 8;
        #pragma unroll
        for (int c = 0; c < 8; c += 2) {
            __half2 hv;
            hv.x = __float2half(fmaxf(accB[c]     * inv + bias[chb + c],     0.f));
            hv.y = __float2half(fmaxf(accB[c + 1] * inv + bias[chb + c + 1], 0.f));
            *(__half2*)&xsh[node * 136 + chb + c] = hv;
        }
    }
}

// ====== fused: conv1 gather (32-dst tile) -> conv2 dual linear via MFMA ======
__launch_bounds__(256)
__global__ void k_gatlin(const __half* __restrict__ xl, const float* __restrict__ xr,
                         const float* __restrict__ att,
                         const int* __restrict__ offs, const int* __restrict__ csr,
                         const float* __restrict__ bias,
                         const __half* __restrict__ Wlt, const float* __restrict__ bl,
                         const __half* __restrict__ Wrt, const float* __restrict__ br,
                         __half* __restrict__ outl, float* __restrict__ outr, int N) {
    __shared__ __align__(16) __half xsh[32 * 136];
    int nb = blockIdx.x * 32;
    gat32_to_lds(xsh, xl, xr, att, offs, csr, bias, nb, N);
    __syncthreads();

    int t = threadIdx.x;
    int lane = t & 63, wv = t >> 6;
    int quad = lane >> 4, n16 = lane & 15;
    int r16 = wv >> 1;              // row-tile (16 nodes)
    int j0 = (wv & 1) * 64;         // col-half for both L and R
    // A fragments: A[m=n16][k=quad*8+i], 4 k-tiles of 32
    f16x8 a[4];
    #pragma unroll
    for (int kt = 0; kt < 4; kt++)
        a[kt] = *(const f16x8*)&xsh[(r16 * 16 + n16) * 136 + kt * 32 + quad * 8];

    f32x4 aL[4], aR[4];
    #pragma unroll
    for (int tl = 0; tl < 4; tl++) { aL[tl] = (f32x4){0.f,0.f,0.f,0.f}; aR[tl] = (f32x4){0.f,0.f,0.f,0.f}; }
    #pragma unroll
    for (int kt = 0; kt < 4; kt++) {
        int ko = kt * 32 + quad * 8;
        #pragma unroll
        for (int tl = 0; tl < 4; tl++) {
            f16x8 bL = *(const f16x8*)&Wlt[(size_t)(j0 + tl * 16 + n16) * 128 + ko];
            f16x8 bR = *(const f16x8*)&Wrt[(size_t)(j0 + tl * 16 + n16) * 128 + ko];
            aL[tl] = __builtin_amdgcn_mfma_f32_16x16x32_f16(a[kt], bL, aL[tl], 0, 0, 0);
            aR[tl] = __builtin_amdgcn_mfma_f32_16x16x32_f16(a[kt], bR, aR[tl], 0, 0, 0);
        }
    }
    float blv[4], brv[4];
    #pragma unroll
    for (int tl = 0; tl < 4; tl++) { blv[tl] = bl[j0 + tl * 16 + n16]; brv[tl] = br[j0 + tl * 16 + n16]; }
    #pragma unroll
    for (int r = 0; r < 4; r++) {
        int node = r16 * 16 + quad * 4 + r;   // D row = node (within row-tile)
        if (nb + node >= N) continue;
        size_t row = (size_t)(nb + node) * 128;
        #pragma unroll
        for (int tl = 0; tl < 4; tl++) {
            outl[row + j0 + tl * 16 + n16] = __float2half(aL[tl][r] + blv[tl]);
            outr[row + j0 + tl * 16 + n16] = aR[tl][r] + brv[tl];
        }
    }
}

// ====== fused: conv2 gather (32-dst tile) -> global linear (FOUT=32) MFMA ====
__launch_bounds__(256)
__global__ void k_gatling(const __half* __restrict__ xl, const float* __restrict__ xr,
                          const float* __restrict__ att,
                          const int* __restrict__ offs, const int* __restrict__ csr,
                          const float* __restrict__ bias,
                          const __half* __restrict__ Wlt, const float* __restrict__ bl,
                          const __half* __restrict__ Wrt, const float* __restrict__ br,
                          __half* __restrict__ outl, float* __restrict__ outr, int N) {
    __shared__ __align__(16) __half xsh[32 * 136];
    int nb = blockIdx.x * 32;
    gat32_to_lds(xsh, xl, xr, att, offs, csr, bias, nb, N);
    __syncthreads();

    int t = threadIdx.x;
    int lane = t & 63, wv = t >> 6;
    int quad = lane >> 4, n16 = lane & 15;
    int r16 = wv >> 1;              // row-tile (16 nodes)
    int side = wv & 1;              // 0 -> L, 1 -> R
    f16x8 a[4];
    #pragma unroll
    for (int kt = 0; kt < 4; kt++)
        a[kt] = *(const f16x8*)&xsh[(r16 * 16 + n16) * 136 + kt * 32 + quad * 8];

    const __half* Wt = side ? Wrt : Wlt;
    f32x4 ac0 = {0.f,0.f,0.f,0.f}, ac1 = {0.f,0.f,0.f,0.f};
    #pragma unroll
    for (int kt = 0; kt < 4; kt++) {
        int ko = kt * 32 + quad * 8;
        f16x8 b0 = *(const f16x8*)&Wt[(size_t)(n16) * 128 + ko];
        f16x8 b1 = *(const f16x8*)&Wt[(size_t)(16 + n16) * 128 + ko];
        ac0 = __builtin_amdgcn_mfma_f32_16x16x32_f16(a[kt], b0, ac0, 0, 0, 0);
        ac1 = __builtin_amdgcn_mfma_f32_16x16x32_f16(a[kt], b1, ac1, 0, 0, 0);
    }
    const float* bb = side ? br : bl;
    float bj0 = bb[n16], bj1 = bb[16 + n16];
    #pragma unroll
    for (int r = 0; r < 4; r++) {
        int node = r16 * 16 + quad * 4 + r;
        if (nb + node >= N) continue;
        size_t row = (size_t)(nb + node) * 32;
        if (side == 0) {
            outl[row + n16]      = __float2half(ac0[r] + bj0);
            outl[row + 16 + n16] = __float2half(ac1[r] + bj1);
        } else {
            outr[row + n16]      = ac0[r] + bj0;
            outr[row + 16 + n16] = ac1[r] + bj1;
        }
    }
}

// ===== tail: global-GAT gather for the 64 FOCAL dsts only + output head =====
__launch_bounds__(64)
__global__ void k_tailf(const __half* __restrict__ xl, const float* __restrict__ xr,
                        const float* __restrict__ att,
                        const int* __restrict__ offs, const int* __restrict__ csr,
                        const float* __restrict__ gb, const int* __restrict__ focal,
                        const float* __restrict__ clf, const float* __restrict__ clW,
                        const float* __restrict__ clb, const float* __restrict__ fcW,
                        const float* __restrict__ fcb, void* __restrict__ out,
                        const int* __restrict__ flag) {
    __shared__ float comb[64];
    __shared__ float ssb[2];
    int b = blockIdx.x;
    int t = threadIdx.x;                  // 64
    int d = focal[b];
    int grp = t >> 3, sub = t & 7;        // 8 edge-groups x 8 lanes (4 ch each)
    int i0 = offs[d], i1 = offs[d + 1];

    float xrd[4], av[4], acc[4];
    {
        float4 a = *(const float4*)(xr + (size_t)d * 32 + sub * 4);
        xrd[0]=a.x; xrd[1]=a.y; xrd[2]=a.z; xrd[3]=a.w;
        float4 c = *(const float4*)(att + sub * 4);
        av[0]=c.x; av[1]=c.y; av[2]=c.z; av[3]=c.w;
    }
    #pragma unroll
    for (int c = 0; c < 4; c++) acc[c] = 0.f;
    float sm = 0.f;

    for (int i = i0 + grp; i < i1; i += 8) {
        float2 raw = *(const float2*)(xl + (size_t)csr[i] * 32 + sub * 4);
        const __half2* h = (const __half2*)&raw;
        float v[4];
        float2 f;
        f = __half22float2(h[0]); v[0] = f.x; v[1] = f.y;
        f = __half22float2(h[1]); v[2] = f.x; v[3] = f.y;
        float p = 0.f;
        #pragma unroll
        for (int c = 0; c < 4; c++) {
            float u = v[c] + xrd[c];
            u = (u > 0.f) ? u : NEG_SLOPE * u;
            p += u * av[c];
        }
        p += __shfl_xor(p, 1);
        p += __shfl_xor(p, 2);
        p += __shfl_xor(p, 4);
        float w = __expf(fminf(p, 80.f));
        sm += w;
        #pragma unroll
        for (int c = 0; c < 4; c++) acc[c] += w * v[c];
    }
    // merge 8 edge-groups
    sm += __shfl_xor(sm, 8); sm += __shfl_xor(sm, 16); sm += __shfl_xor(sm, 32);
    #pragma unroll
    for (int c = 0; c < 4; c++) {
        acc[c] += __shfl_xor(acc[c], 8);
        acc[c] += __shfl_xor(acc[c], 16);
        acc[c] += __shfl_xor(acc[c], 32);
    }
    if (grp == 0) {
        float inv = 1.f / (sm + 1e-16f);
        #pragma unroll
        for (int c = 0; c < 4; c++)
            comb[sub * 4 + c] = fmaxf(acc[c] * inv + gb[sub * 4 + c], 0.f);
    }
    if (t < 2) {
        float s = 0.f;
        for (int l = 0; l < 50; l++) s += clf[(size_t)b * 100 + l * 2 + t];
        ssb[t] = s / 50.f;
    }
    __syncthreads();
    if (t < 32) comb[32 + t] = ssb[0] * clW[t] + ssb[1] * clW[32 + t] + clb[t];
    __syncthreads();
    if (t < 60) {
        float a2 = fcb[t];
        #pragma unroll 16
        for (int k = 0; k < 64; k++) a2 += comb[k] * fcW[k * 60 + t];
        if (flag[0]) ((float*)out)[b * 60 + t] = a2;
        else ((bf16*)out)[b * 60 + t] = __float2bfloat16(a2);
    }
}

extern "C" void kernel_launch(void* const* d_in, const int* in_sizes, int n_in,
                              void* d_out, int out_size, void* d_ws, size_t ws_size,
                              hipStream_t stream) {
    const int* edge  = (const int*)d_in[1];
    const int* focal = (const int*)d_in[5];

    const int N = in_sizes[0] / 100;   // 20000
    const int E = in_sizes[1] / 2;     // 320000
    const int B = in_sizes[5];         // 64
    const int EA = E + N;
    const int* srcArr = edge;
    const int* dstArr = edge + E;

    // ---- conversion table: weights + centerlines -> fp32 in ws (x stays raw)
    const int idxs[NSEG] = {7,8,9,10,11,12,13,14,15,16,17,18,19,20,
                            35,36,37,38,39,40,41,42,43,44, 6};
    float* base = (float*)d_ws;
    int* flag = (int*)base;            // base[0..15] reserved
    float* wf = base + 16;
    Tab tab;
    int off[NSEG];
    int o = 0;
    for (int i = 0; i < NSEG; i++) {
        tab.s[i].src = d_in[idxs[i]];
        tab.s[i].n   = in_sizes[idxs[i]];
        tab.s[i].off = o;
        off[i] = o;
        o += in_sizes[idxs[i]];
    }
    const float* aeW  = wf + off[0],  *aeb  = wf + off[1];
    const float* a1Wl = wf + off[2],  *a1bl = wf + off[3];
    const float* a1Wr = wf + off[4],  *a1br = wf + off[5];
    const float* a1att= wf + off[6],  *a1b  = wf + off[7];
    const float* a2bl = wf + off[9];
    const float* a2br = wf + off[11];
    const float* a2att= wf + off[12], *a2b  = wf + off[13];
    const float* clW  = wf + off[14], *clb  = wf + off[15];
    const float* gbl  = wf + off[17];
    const float* gbr  = wf + off[19];
    const float* gatt = wf + off[20], *gb   = wf + off[21];
    const float* fcW  = wf + off[22], *fcb  = wf + off[23];
    const float* clf  = wf + off[24];

    // ---- remaining workspace (keep 16B alignment) ----
    float* p = wf + o + ((4 - (o & 3)) & 3);
    size_t N128 = (size_t)N * 128;
    __half* hxl1 = (__half*)p;      p += (size_t)N * 64;    // conv1 xl fp16 [N,128]; later global xl [N,32]
    float* fB1  = p;                p += N128;              // conv1 xr fp32; later global xrg [N,32]
    __half* hxl2 = (__half*)p;      p += (size_t)N * 64;    // conv2 xl fp16 [N,128]
    float* fB2  = p;                p += N128;              // conv2 xr fp32
    int* deg    = (int*)p;          // [N]
    int* st     = deg + N;          // [32] scan lookback state
    int* offs   = st + 32;          // N+1
    int* rank   = offs + N + 1;     // EA
    int* csr    = rank + EA;        // EA (src node ids)
    // transposed f16 weights (16B aligned)
    uintptr_t up = (uintptr_t)(csr + EA);
    up = (up + 15) & ~(uintptr_t)15;
    __half* a2Wlt = (__half*)up;    // [128][128]
    __half* a2Wrt = a2Wlt + 16384;  // [128][128]
    __half* gWlt  = a2Wrt + 16384;  // [32][128]
    __half* gWrt  = gWlt + 4096;    // [32][128]

    const int NB = (N + 1023) / 1024;          // scan tiles (20)
    const int EB = N / 32;                     // embedlin blocks (625)
    const int FBLK = (EA + 255) / 256;         // fill blocks
    const int GT = (N + 31) / 32;              // fused gather+linear tiles (625)

    // ---- detect + zero deg/st ----
    k_detect_zero<<<64, 256, 0, stream>>>((const unsigned short*)d_in[0], flag, deg, N + 32);
    // ---- convert weights (+ f16 transposed) + degree count with rank capture
    k_convert<<<256, 256, 0, stream>>>(tab, wf, flag, dstArr, E, N, deg, rank,
                                       d_in[15], d_in[17], d_in[37], d_in[39],
                                       a2Wlt, a2Wrt, gWlt, gWrt);
    // ---- single-kernel lookback scan ----
    k_scanf<<<NB, 1024, 0, stream>>>(deg, offs, N, st, NB);
    // ---- CSR fill (rank trick) + fused embed+conv1-linear -> hxl1/fB1 ----
    k_fill_embedlin<<<EB + FBLK, 256, 0, stream>>>(srcArr, dstArr, E, N, offs, rank, csr,
                                                   d_in[0], flag, aeW, aeb,
                                                   a1Wl, a1bl, a1Wr, a1br, hxl1, fB1, EB);
    // ---- conv1 gather + conv2 linear (MFMA, fC stays in LDS) -> hxl2/fB2 ----
    k_gatlin<<<GT, 256, 0, stream>>>(hxl1, fB1, a1att, offs, csr, a1b,
                                     a2Wlt, a2bl, a2Wrt, a2br, hxl2, fB2, N);
    // ---- conv2 gather + global linear (MFMA) -> hxl1([N,32]) / fB1([N,32]) --
    k_gatling<<<GT, 256, 0, stream>>>(hxl2, fB2, a2att, offs, csr, a2b,
                                      gWlt, gbl, gWrt, gbr, hxl1, fB1, N);
    // ---- tail: global gather for the 64 focal dsts + head ----
    k_tailf<<<B, 64, 0, stream>>>(hxl1, fB1, gatt, offs, csr, gb, focal,
                                  clf, clW, clb, fcW, fcb, d_out, flag);
}

// Round 3
// 274.862 us; speedup vs baseline: 1.0417x; 1.0417x over previous
//
#include <hip/hip_runtime.h>
#include <hip/hip_bf16.h>
#include <hip/hip_fp16.h>
#include <math.h>

typedef __hip_bfloat16 bf16;
#define NEG_SLOPE 0.2f
#define SFLAG (1 << 30)

typedef _Float16 f16x8 __attribute__((ext_vector_type(8)));
typedef float f32x4 __attribute__((ext_vector_type(4)));

// ====== dtype detect (block 0) + zero deg/scan-state =========================
__global__ void k_detect_zero(const unsigned short* __restrict__ x, int* __restrict__ flag,
                              int* __restrict__ zbase, int n) {
    for (int i = blockIdx.x * blockDim.x + threadIdx.x; i < n; i += gridDim.x * blockDim.x)
        zbase[i] = 0;
    if (blockIdx.x == 0) {
        __shared__ int cnt;
        if (threadIdx.x == 0) cnt = 0;
        __syncthreads();
        int local = 0;
        for (int i = threadIdx.x; i < 2048; i += blockDim.x) {
            unsigned short w = x[2 * i];
            int e = (w >> 7) & 0xFF;
            if (e >= 0x90) local++;
        }
        atomicAdd(&cnt, local);
        __syncthreads();
        if (threadIdx.x == 0) flag[0] = (cnt > 100) ? 1 : 0;  // 1 => inputs are f32
    }
}

#define NSEG 25
struct Seg { const void* src; int n; int off; };
struct Tab { Seg s[NSEG]; };

__device__ __forceinline__ float ldconv(const void* src, int i, int f32mode) {
    return f32mode ? ((const float*)src)[i]
                   : __bfloat162float(((const bf16*)src)[i]);
}

// ====== convert weights fp32 + transposed f16 weights + degree/rank ==========
__global__ void k_convert(Tab tab, float* __restrict__ dst, const int* __restrict__ flag,
                          const int* __restrict__ dstArr, int E, int N,
                          int* __restrict__ deg, int* __restrict__ rank,
                          const void* a2WlS, const void* a2WrS,
                          const void* gWlS, const void* gWrS,
                          __half* __restrict__ a2Wlt, __half* __restrict__ a2Wrt,
                          __half* __restrict__ gWlt, __half* __restrict__ gWrt) {
    int f32mode = flag[0];
    int gid = blockIdx.x * blockDim.x + threadIdx.x;
    int gsz = gridDim.x * blockDim.x;
    for (int s = 0; s < NSEG; s++) {
        Seg sg = tab.s[s];
        for (int i = gid; i < sg.n; i += gsz) {
            dst[sg.off + i] = ldconv(sg.src, i, f32mode);
        }
    }
    // transposed f16 weights: Wt[j][k] = W[k][j]
    for (int i = gid; i < 128 * 128; i += gsz) {
        int k = i >> 7, j = i & 127;
        a2Wlt[(size_t)j * 128 + k] = __float2half(ldconv(a2WlS, i, f32mode));
        a2Wrt[(size_t)j * 128 + k] = __float2half(ldconv(a2WrS, i, f32mode));
    }
    for (int i = gid; i < 128 * 32; i += gsz) {
        int k = i >> 5, j = i & 31;
        gWlt[(size_t)j * 128 + k] = __float2half(ldconv(gWlS, i, f32mode));
        gWrt[(size_t)j * 128 + k] = __float2half(ldconv(gWrS, i, f32mode));
    }
    int EA = E + N;
    for (int e = gid; e < EA; e += gsz) {
        int d = (e < E) ? dstArr[e] : (e - E);
        rank[e] = atomicAdd(&deg[d], 1);
    }
}

// ====== single-kernel chained-lookback exclusive scan ========================
__launch_bounds__(1024)
__global__ void k_scanf(const int* __restrict__ deg, int* __restrict__ offs,
                        int n, int* __restrict__ st, int nb) {
    __shared__ int ws[16];
    __shared__ int stot, sprev;
    int tile = blockIdx.x;
    int i = tile * 1024 + threadIdx.x;
    int lane = threadIdx.x & 63, wid = threadIdx.x >> 6;
    int v = (i < n) ? deg[i] : 0;
    int x = v;
    #pragma unroll
    for (int o = 1; o < 64; o <<= 1) {
        int y = __shfl_up(x, o);
        if (lane >= o) x += y;
    }
    if (lane == 63) ws[wid] = x;
    __syncthreads();
    if (wid == 0) {
        int w = (lane < 16) ? ws[lane] : 0;
        int s = w;
        #pragma unroll
        for (int o = 1; o < 16; o <<= 1) {
            int y = __shfl_up(s, o);
            if (lane >= o) s += y;
        }
        if (lane < 16) ws[lane] = s - w;
        if (lane == 15) stot = s;
    }
    __syncthreads();
    int local = ws[wid] + x - v;     // block-local exclusive
    if (threadIdx.x == 0) {
        int prev = 0;
        if (tile > 0) {
            int vv;
            while ((((vv = __hip_atomic_load(&st[tile - 1], __ATOMIC_ACQUIRE,
                                             __HIP_MEMORY_SCOPE_AGENT))) & SFLAG) == 0) {}
            prev = vv & ~SFLAG;
        }
        __hip_atomic_store(&st[tile], (prev + stot) | SFLAG, __ATOMIC_RELEASE,
                           __HIP_MEMORY_SCOPE_AGENT);
        sprev = prev;
        if (tile == nb - 1) offs[n] = prev + stot;
    }
    __syncthreads();
    if (i < n) offs[i] = sprev + local;
}

// ====== fused: CSR fill via rank (blocks >= EB) + embed+conv1-linear =========
__launch_bounds__(256)
__global__ void k_fill_embedlin(const int* __restrict__ srcArr, const int* __restrict__ dstArr,
                                int E, int N, const int* __restrict__ offs,
                                const int* __restrict__ rank, int* __restrict__ csr,
                                const void* __restrict__ xraw, const int* __restrict__ flag,
                                const float* __restrict__ aeW, const float* __restrict__ aeb,
                                const float* __restrict__ Wl, const float* __restrict__ bl,
                                const float* __restrict__ Wr, const float* __restrict__ br,
                                __half* __restrict__ outl, float* __restrict__ outr,
                                int EB) {
    __shared__ float xs[100 * 36];
    __shared__ float axs[32 * 36];
    if (blockIdx.x >= EB) {
        int e = (blockIdx.x - EB) * 256 + threadIdx.x;
        int EA = E + N;
        if (e >= EA) return;
        int d, s;
        if (e < E) { d = dstArr[e]; s = srcArr[e]; } else { d = s = e - E; }
        csr[offs[d] + rank[e]] = s;     // no atomics: rank captured during count
        return;
    }
    constexpr int NTP = 36;
    int t = threadIdx.x, nb = blockIdx.x * 32;
    if (flag[0]) {
        const float4* x4 = (const float4*)xraw;
        for (int idx = t; idx < 32 * 25; idx += 256) {
            int node = idx / 25, k4 = idx % 25;
            float4 v = x4[(size_t)(nb + node) * 25 + k4];
            xs[(k4 * 4 + 0) * NTP + node] = v.x;
            xs[(k4 * 4 + 1) * NTP + node] = v.y;
            xs[(k4 * 4 + 2) * NTP + node] = v.z;
            xs[(k4 * 4 + 3) * NTP + node] = v.w;
        }
    } else {
        const ushort4* xu = (const ushort4*)xraw;
        for (int idx = t; idx < 32 * 25; idx += 256) {
            int node = idx / 25, k4 = idx % 25;
            ushort4 u = xu[(size_t)(nb + node) * 25 + k4];
            xs[(k4 * 4 + 0) * NTP + node] = __uint_as_float((unsigned)u.x << 16);
            xs[(k4 * 4 + 1) * NTP + node] = __uint_as_float((unsigned)u.y << 16);
            xs[(k4 * 4 + 2) * NTP + node] = __uint_as_float((unsigned)u.z << 16);
            xs[(k4 * 4 + 3) * NTP + node] = __uint_as_float((unsigned)u.w << 16);
        }
    }
    __syncthreads();
    {
        int j = t & 31, g0 = t >> 5;
        float a0 = 0.f, a1 = 0.f, a2 = 0.f, a3 = 0.f;
        #pragma unroll 10
        for (int k = 0; k < 100; k++) {
            float w = aeW[k * 32 + j];
            const float4 xv = *(const float4*)&xs[k * NTP + g0 * 4];
            a0 += w * xv.x; a1 += w * xv.y; a2 += w * xv.z; a3 += w * xv.w;
        }
        float bj = aeb[j];
        axs[j * NTP + g0 * 4 + 0] = fmaxf(a0 + bj, 0.f);
        axs[j * NTP + g0 * 4 + 1] = fmaxf(a1 + bj, 0.f);
        axs[j * NTP + g0 * 4 + 2] = fmaxf(a2 + bj, 0.f);
        axs[j * NTP + g0 * 4 + 3] = fmaxf(a3 + bj, 0.f);
    }
    __syncthreads();
    {
        int j = t & 63, g0 = t >> 6;
        float aL0[2][4], aL1[2][4], aR0[2][4], aR1[2][4];
        #pragma unroll
        for (int g = 0; g < 2; g++)
            #pragma unroll
            for (int c = 0; c < 4; c++) { aL0[g][c]=0.f; aL1[g][c]=0.f; aR0[g][c]=0.f; aR1[g][c]=0.f; }
        #pragma unroll 4
        for (int k = 0; k < 32; k++) {
            float wl0 = Wl[k * 128 + j];
            float wl1 = Wl[k * 128 + j + 64];
            float wr0 = Wr[k * 128 + j];
            float wr1 = Wr[k * 128 + j + 64];
            #pragma unroll
            for (int g = 0; g < 2; g++) {
                const float4 xv = *(const float4*)&axs[k * NTP + (g0 + g * 4) * 4];
                aL0[g][0] += wl0 * xv.x; aL0[g][1] += wl0 * xv.y; aL0[g][2] += wl0 * xv.z; aL0[g][3] += wl0 * xv.w;
                aL1[g][0] += wl1 * xv.x; aL1[g][1] += wl1 * xv.y; aL1[g][2] += wl1 * xv.z; aL1[g][3] += wl1 * xv.w;
                aR0[g][0] += wr0 * xv.x; aR0[g][1] += wr0 * xv.y; aR0[g][2] += wr0 * xv.z; aR0[g][3] += wr0 * xv.w;
                aR1[g][0] += wr1 * xv.x; aR1[g][1] += wr1 * xv.y; aR1[g][2] += wr1 * xv.z; aR1[g][3] += wr1 * xv.w;
            }
        }
        float bl0 = bl[j], bl1 = bl[j + 64], br0 = br[j], br1 = br[j + 64];
        #pragma unroll
        for (int g = 0; g < 2; g++) {
            int n0 = nb + (g0 + g * 4) * 4;
            #pragma unroll
            for (int c = 0; c < 4; c++) {
                size_t row = (size_t)(n0 + c) * 128;
                outl[row + j]      = __float2half(aL0[g][c] + bl0);
                outl[row + j + 64] = __float2half(aL1[g][c] + bl1);
                outr[row + j]      = aR0[g][c] + br0;
                outr[row + j + 64] = aR1[g][c] + br1;
            }
        }
    }
}

// ====== per-edge math (16-lane group, 8 channels/lane) =======================
__device__ __forceinline__ void gat_proc(float4 raw, bool valid,
                                         const float* xrd, const float* av,
                                         float* acc, float& sm) {
    const __half2* h = (const __half2*)&raw;
    float v[8];
    float2 f;
    f = __half22float2(h[0]); v[0] = f.x; v[1] = f.y;
    f = __half22float2(h[1]); v[2] = f.x; v[3] = f.y;
    f = __half22float2(h[2]); v[4] = f.x; v[5] = f.y;
    f = __half22float2(h[3]); v[6] = f.x; v[7] = f.y;
    float p = 0.f;
    #pragma unroll
    for (int c = 0; c < 8; c++) {
        float u = v[c] + xrd[c];
        u = (u > 0.f) ? u : NEG_SLOPE * u;
        p += u * av[c];
    }
    p += __shfl_xor(p, 1);
    p += __shfl_xor(p, 2);
    p += __shfl_xor(p, 4);
    p += __shfl_xor(p, 8);
    float w = __expf(fminf(p, 80.f));
    if (!valid) w = 0.f;
    sm += w;
    #pragma unroll
    for (int c = 0; c < 8; c++) acc[c] += w * v[c];
}

// ====== GAT H=4 gather of a 16-dst tile into LDS (fp16, node-major) ==========
// One dst per 16-lane group (round-1 shape: max TLP, 1250 blocks). New: all
// csr indices preloaded into 3 regs (deg<=48 covers the real graph), and a
// 2-stage A/B software pipeline at 4-edge granularity -> 8 xl-row loads in
// flight per group (32/wave), no csr latency in the steady-state chain.
// xsh layout: xsh[node * 136 + ch], node in [0,16), ch in [0,128). 4.35 KB.
__device__ __forceinline__ void gat16_to_lds(__half* xsh,
                                             const __half* __restrict__ xl,
                                             const float* __restrict__ xr,
                                             const float* __restrict__ att,
                                             const int* __restrict__ offs,
                                             const int* __restrict__ csr,
                                             const float* __restrict__ bias,
                                             int nb, int N) {
    int t = threadIdx.x;
    int wave = t >> 6, lane = t & 63;
    int grp = lane >> 4, sub = lane & 15;     // group owns one dst
    int lb = lane & 48;                       // group base lane
    float av[8];
    {
        const float4* t4 = (const float4*)(att + sub * 8);
        float4 c = t4[0], e = t4[1];
        av[0]=c.x; av[1]=c.y; av[2]=c.z; av[3]=c.w;
        av[4]=e.x; av[5]=e.y; av[6]=e.z; av[7]=e.w;
    }
    int d = nb + wave * 4 + grp;
    bool ok = d < N;
    int i0 = ok ? offs[d] : 0;
    int i1 = ok ? offs[d + 1] : 0;
    int cnt = i1 - i0;

    float xrd[8];
    #pragma unroll
    for (int c = 0; c < 8; c++) xrd[c] = 0.f;
    if (ok) {
        const float4* p4 = (const float4*)(xr + (size_t)d * 128 + sub * 8);
        float4 a = p4[0], b = p4[1];
        xrd[0]=a.x; xrd[1]=a.y; xrd[2]=a.z; xrd[3]=a.w;
        xrd[4]=b.x; xrd[5]=b.y; xrd[6]=b.z; xrd[7]=b.w;
    }
    float acc[8];
    #pragma unroll
    for (int c = 0; c < 8; c++) acc[c] = 0.f;
    float sm = 0.f;

    // preload up to 48 edge indices into regs (covers all realistic degrees)
    int m0 = (sub < cnt)      ? csr[i0 + sub]      : 0;
    int m1 = (16 + sub < cnt) ? csr[i0 + 16 + sub] : 0;
    int m2 = (32 + sub < cnt) ? csr[i0 + 32 + sub] : 0;

    int cmain = cnt < 48 ? cnt : 48;
    int nbat = (cmain + 3) >> 2;              // 4-edge batches

    float4 rA0, rA1, rA2, rA3, rB0, rB1, rB2, rB3;
    auto FETCH = [&](int b, float4& q0, float4& q1, float4& q2, float4& q3) {
        int mreg = (b < 4) ? m0 : ((b < 8) ? m1 : m2);
        int base = lb + (b & 3) * 4;
        int s0 = __shfl(mreg, base + 0);
        int s1 = __shfl(mreg, base + 1);
        int s2 = __shfl(mreg, base + 2);
        int s3 = __shfl(mreg, base + 3);
        q0 = *(const float4*)(xl + (size_t)s0 * 128 + sub * 8);
        q1 = *(const float4*)(xl + (size_t)s1 * 128 + sub * 8);
        q2 = *(const float4*)(xl + (size_t)s2 * 128 + sub * 8);
        q3 = *(const float4*)(xl + (size_t)s3 * 128 + sub * 8);
    };

    FETCH(0, rA0, rA1, rA2, rA3);
    int nb2 = (nbat + 1) & ~1;                // round up to even
    for (int b = 0; b < nb2; b += 2) {
        bool hasB = (b + 1 < nbat);
        if (hasB) FETCH(b + 1, rB0, rB1, rB2, rB3);
        int e0 = b * 4;
        gat_proc(rA0, true,           xrd, av, acc, sm);   // b < nbat => e0 < cmain
        gat_proc(rA1, e0 + 1 < cmain, xrd, av, acc, sm);
        gat_proc(rA2, e0 + 2 < cmain, xrd, av, acc, sm);
        gat_proc(rA3, e0 + 3 < cmain, xrd, av, acc, sm);
        if (b + 2 < nbat) FETCH(b + 2, rA0, rA1, rA2, rA3);
        if (hasB) {
            int e1 = e0 + 4;
            gat_proc(rB0, true,           xrd, av, acc, sm);
            gat_proc(rB1, e1 + 1 < cmain, xrd, av, acc, sm);
            gat_proc(rB2, e1 + 2 < cmain, xrd, av, acc, sm);
            gat_proc(rB3, e1 + 3 < cmain, xrd, av, acc, sm);
        }
    }

    // rare tail (deg > 48): correctness-only path
    for (int base = 48; base < cnt; base += 16) {
        int mm = (base + sub < cnt) ? csr[i0 + base + sub] : 0;
        int rem = cnt - base; if (rem > 16) rem = 16;
        for (int k = 0; k < rem; k += 4) {
            int s0 = __shfl(mm, lb + k + 0);
            int s1 = __shfl(mm, lb + k + 1);
            int s2 = __shfl(mm, lb + k + 2);
            int s3 = __shfl(mm, lb + k + 3);
            float4 q0 = *(const float4*)(xl + (size_t)s0 * 128 + sub * 8);
            float4 q1 = *(const float4*)(xl + (size_t)s1 * 128 + sub * 8);
            float4 q2 = *(const float4*)(xl + (size_t)s2 * 128 + sub * 8);
            float4 q3 = *(const float4*)(xl + (size_t)s3 * 128 + sub * 8);
            gat_proc(q0, true,        xrd, av, acc, sm);
            gat_proc(q1, k + 1 < rem, xrd, av, acc, sm);
            gat_proc(q2, k + 2 < rem, xrd, av, acc, sm);
            gat_proc(q3, k + 3 < rem, xrd, av, acc, sm);
        }
    }

    // acc is already the full per-dst sum (group's 16 lanes cover 128 ch)
    if (ok) {
        float inv = 1.f / (sm + 1e-16f);
        int node = wave * 4 + grp;
        int ch = sub * 8;
        #pragma unroll
        for (int c = 0; c < 8; c += 2) {
            __half2 hv;
            hv.x = __float2half(fmaxf(acc[c]     * inv + bias[ch + c],     0.f));
            hv.y = __float2half(fmaxf(acc[c + 1] * inv + bias[ch + c + 1], 0.f));
            *(__half2*)&xsh[node * 136 + ch + c] = hv;
        }
    }
}

// ====== fused: conv1 gather (16-dst tile) -> conv2 dual linear via MFMA ======
__launch_bounds__(256)
__global__ void k_gatlin(const __half* __restrict__ xl, const float* __restrict__ xr,
                         const float* __restrict__ att,
                         const int* __restrict__ offs, const int* __restrict__ csr,
                         const float* __restrict__ bias,
                         const __half* __restrict__ Wlt, const float* __restrict__ bl,
                         const __half* __restrict__ Wrt, const float* __restrict__ br,
                         __half* __restrict__ outl, float* __restrict__ outr, int N) {
    __shared__ __align__(16) __half xsh[16 * 136];
    int nb = blockIdx.x * 16;
    gat16_to_lds(xsh, xl, xr, att, offs, csr, bias, nb, N);
    __syncthreads();

    int t = threadIdx.x;
    int lane = t & 63, wv = t >> 6;
    int quad = lane >> 4, n16 = lane & 15;
    // A fragments: A[m=lane&15][k=quad*8+i], 4 k-tiles of 32
    f16x8 a[4];
    #pragma unroll
    for (int kt = 0; kt < 4; kt++)
        a[kt] = *(const f16x8*)&xsh[n16 * 136 + kt * 32 + quad * 8];

    int j0 = wv * 32;   // this wave's 32 output columns (two 16-tiles), for L and R
    f32x4 aL0 = {0.f,0.f,0.f,0.f}, aL1 = {0.f,0.f,0.f,0.f};
    f32x4 aR0 = {0.f,0.f,0.f,0.f}, aR1 = {0.f,0.f,0.f,0.f};
    #pragma unroll
    for (int kt = 0; kt < 4; kt++) {
        int ko = kt * 32 + quad * 8;
        f16x8 b0 = *(const f16x8*)&Wlt[(size_t)(j0 + n16) * 128 + ko];
        f16x8 b1 = *(const f16x8*)&Wlt[(size_t)(j0 + 16 + n16) * 128 + ko];
        f16x8 b2 = *(const f16x8*)&Wrt[(size_t)(j0 + n16) * 128 + ko];
        f16x8 b3 = *(const f16x8*)&Wrt[(size_t)(j0 + 16 + n16) * 128 + ko];
        aL0 = __builtin_amdgcn_mfma_f32_16x16x32_f16(a[kt], b0, aL0, 0, 0, 0);
        aL1 = __builtin_amdgcn_mfma_f32_16x16x32_f16(a[kt], b1, aL1, 0, 0, 0);
        aR0 = __builtin_amdgcn_mfma_f32_16x16x32_f16(a[kt], b2, aR0, 0, 0, 0);
        aR1 = __builtin_amdgcn_mfma_f32_16x16x32_f16(a[kt], b3, aR1, 0, 0, 0);
    }
    float blj0 = bl[j0 + n16], blj1 = bl[j0 + 16 + n16];
    float brj0 = br[j0 + n16], brj1 = br[j0 + 16 + n16];
    #pragma unroll
    for (int r = 0; r < 4; r++) {
        int node = quad * 4 + r;        // D row = node
        if (nb + node >= N) continue;
        size_t row = (size_t)(nb + node) * 128;
        outl[row + j0 + n16]      = __float2half(aL0[r] + blj0);
        outl[row + j0 + 16 + n16] = __float2half(aL1[r] + blj1);
        outr[row + j0 + n16]      = aR0[r] + brj0;
        outr[row + j0 + 16 + n16] = aR1[r] + brj1;
    }
}

// ====== fused: conv2 gather (16-dst tile) -> global linear (FOUT=32) MFMA ====
__launch_bounds__(256)
__global__ void k_gatling(const __half* __restrict__ xl, const float* __restrict__ xr,
                          const float* __restrict__ att,
                          const int* __restrict__ offs, const int* __restrict__ csr,
                          const float* __restrict__ bias,
                          const __half* __restrict__ Wlt, const float* __restrict__ bl,
                          const __half* __restrict__ Wrt, const float* __restrict__ br,
                          __half* __restrict__ outl, float* __restrict__ outr, int N) {
    __shared__ __align__(16) __half xsh[16 * 136];
    int nb = blockIdx.x * 16;
    gat16_to_lds(xsh, xl, xr, att, offs, csr, bias, nb, N);
    __syncthreads();

    int t = threadIdx.x;
    int lane = t & 63, wv = t >> 6;
    int quad = lane >> 4, n16 = lane & 15;
    f16x8 a[4];
    #pragma unroll
    for (int kt = 0; kt < 4; kt++)
        a[kt] = *(const f16x8*)&xsh[n16 * 136 + kt * 32 + quad * 8];

    // wave -> one 16x16 tile: wv 0: L j0=0; 1: L j0=16; 2: R j0=0; 3: R j0=16
    const __half* Wt = (wv < 2) ? Wlt : Wrt;
    int j0 = (wv & 1) * 16;
    f32x4 accv = {0.f,0.f,0.f,0.f};
    #pragma unroll
    for (int kt = 0; kt < 4; kt++) {
        f16x8 b = *(const f16x8*)&Wt[(size_t)(j0 + n16) * 128 + kt * 32 + quad * 8];
        accv = __builtin_amdgcn_mfma_f32_16x16x32_f16(a[kt], b, accv, 0, 0, 0);
    }
    float bj = ((wv < 2) ? bl : br)[j0 + n16];
    #pragma unroll
    for (int r = 0; r < 4; r++) {
        int node = quad * 4 + r;
        if (nb + node >= N) continue;
        size_t row = (size_t)(nb + node) * 32;
        if (wv < 2) outl[row + j0 + n16] = __float2half(accv[r] + bj);
        else        outr[row + j0 + n16] = accv[r] + bj;
    }
}

// ===== tail: global-GAT gather for the 64 FOCAL dsts only + output head =====
__launch_bounds__(64)
__global__ void k_tailf(const __half* __restrict__ xl, const float* __restrict__ xr,
                        const float* __restrict__ att,
                        const int* __restrict__ offs, const int* __restrict__ csr,
                        const float* __restrict__ gb, const int* __restrict__ focal,
                        const float* __restrict__ clf, const float* __restrict__ clW,
                        const float* __restrict__ clb, const float* __restrict__ fcW,
                        const float* __restrict__ fcb, void* __restrict__ out,
                        const int* __restrict__ flag) {
    __shared__ float comb[64];
    __shared__ float ssb[2];
    int b = blockIdx.x;
    int t = threadIdx.x;                  // 64
    int d = focal[b];
    int grp = t >> 3, sub = t & 7;        // 8 edge-groups x 8 lanes (4 ch each)
    int i0 = offs[d], i1 = offs[d + 1];

    float xrd[4], av[4], acc[4];
    {
        float4 a = *(const float4*)(xr + (size_t)d * 32 + sub * 4);
        xrd[0]=a.x; xrd[1]=a.y; xrd[2]=a.z; xrd[3]=a.w;
        float4 c = *(const float4*)(att + sub * 4);
        av[0]=c.x; av[1]=c.y; av[2]=c.z; av[3]=c.w;
    }
    #pragma unroll
    for (int c = 0; c < 4; c++) acc[c] = 0.f;
    float sm = 0.f;

    for (int i = i0 + grp; i < i1; i += 8) {
        float2 raw = *(const float2*)(xl + (size_t)csr[i] * 32 + sub * 4);
        const __half2* h = (const __half2*)&raw;
        float v[4];
        float2 f;
        f = __half22float2(h[0]); v[0] = f.x; v[1] = f.y;
        f = __half22float2(h[1]); v[2] = f.x; v[3] = f.y;
        float p = 0.f;
        #pragma unroll
        for (int c = 0; c < 4; c++) {
            float u = v[c] + xrd[c];
            u = (u > 0.f) ? u : NEG_SLOPE * u;
            p += u * av[c];
        }
        p += __shfl_xor(p, 1);
        p += __shfl_xor(p, 2);
        p += __shfl_xor(p, 4);
        float w = __expf(fminf(p, 80.f));
        sm += w;
        #pragma unroll
        for (int c = 0; c < 4; c++) acc[c] += w * v[c];
    }
    // merge 8 edge-groups
    sm += __shfl_xor(sm, 8); sm += __shfl_xor(sm, 16); sm += __shfl_xor(sm, 32);
    #pragma unroll
    for (int c = 0; c < 4; c++) {
        acc[c] += __shfl_xor(acc[c], 8);
        acc[c] += __shfl_xor(acc[c], 16);
        acc[c] += __shfl_xor(acc[c], 32);
    }
    if (grp == 0) {
        float inv = 1.f / (sm + 1e-16f);
        #pragma unroll
        for (int c = 0; c < 4; c++)
            comb[sub * 4 + c] = fmaxf(acc[c] * inv + gb[sub * 4 + c], 0.f);
    }
    if (t < 2) {
        float s = 0.f;
        for (int l = 0; l < 50; l++) s += clf[(size_t)b * 100 + l * 2 + t];
        ssb[t] = s / 50.f;
    }
    __syncthreads();
    if (t < 32) comb[32 + t] = ssb[0] * clW[t] + ssb[1] * clW[32 + t] + clb[t];
    __syncthreads();
    if (t < 60) {
        float a2 = fcb[t];
        #pragma unroll 16
        for (int k = 0; k < 64; k++) a2 += comb[k] * fcW[k * 60 + t];
        if (flag[0]) ((float*)out)[b * 60 + t] = a2;
        else ((bf16*)out)[b * 60 + t] = __float2bfloat16(a2);
    }
}

extern "C" void kernel_launch(void* const* d_in, const int* in_sizes, int n_in,
                              void* d_out, int out_size, void* d_ws, size_t ws_size,
                              hipStream_t stream) {
    const int* edge  = (const int*)d_in[1];
    const int* focal = (const int*)d_in[5];

    const int N = in_sizes[0] / 100;   // 20000
    const int E = in_sizes[1] / 2;     // 320000
    const int B = in_sizes[5];         // 64
    const int EA = E + N;
    const int* srcArr = edge;
    const int* dstArr = edge + E;

    // ---- conversion table: weights + centerlines -> fp32 in ws (x stays raw)
    const int idxs[NSEG] = {7,8,9,10,11,12,13,14,15,16,17,18,19,20,
                            35,36,37,38,39,40,41,42,43,44, 6};
    float* base = (float*)d_ws;
    int* flag = (int*)base;            // base[0..15] reserved
    float* wf = base + 16;
    Tab tab;
    int off[NSEG];
    int o = 0;
    for (int i = 0; i < NSEG; i++) {
        tab.s[i].src = d_in[idxs[i]];
        tab.s[i].n   = in_sizes[idxs[i]];
        tab.s[i].off = o;
        off[i] = o;
        o += in_sizes[idxs[i]];
    }
    const float* aeW  = wf + off[0],  *aeb  = wf + off[1];
    const float* a1Wl = wf + off[2],  *a1bl = wf + off[3];
    const float* a1Wr = wf + off[4],  *a1br = wf + off[5];
    const float* a1att= wf + off[6],  *a1b  = wf + off[7];
    const float* a2bl = wf + off[9];
    const float* a2br = wf + off[11];
    const float* a2att= wf + off[12], *a2b  = wf + off[13];
    const float* clW  = wf + off[14], *clb  = wf + off[15];
    const float* gbl  = wf + off[17];
    const float* gbr  = wf + off[19];
    const float* gatt = wf + off[20], *gb   = wf + off[21];
    const float* fcW  = wf + off[22], *fcb  = wf + off[23];
    const float* clf  = wf + off[24];

    // ---- remaining workspace (keep 16B alignment) ----
    float* p = wf + o + ((4 - (o & 3)) & 3);
    size_t N128 = (size_t)N * 128;
    __half* hxl1 = (__half*)p;      p += (size_t)N * 64;    // conv1 xl fp16 [N,128]; later global xl [N,32]
    float* fB1  = p;                p += N128;              // conv1 xr fp32; later global xrg [N,32]
    __half* hxl2 = (__half*)p;      p += (size_t)N * 64;    // conv2 xl fp16 [N,128]
    float* fB2  = p;                p += N128;              // conv2 xr fp32
    int* deg    = (int*)p;          // [N]
    int* st     = deg + N;          // [32] scan lookback state
    int* offs   = st + 32;          // N+1
    int* rank   = offs + N + 1;     // EA
    int* csr    = rank + EA;        // EA (src node ids)
    // transposed f16 weights (16B aligned)
    uintptr_t up = (uintptr_t)(csr + EA);
    up = (up + 15) & ~(uintptr_t)15;
    __half* a2Wlt = (__half*)up;    // [128][128]
    __half* a2Wrt = a2Wlt + 16384;  // [128][128]
    __half* gWlt  = a2Wrt + 16384;  // [32][128]
    __half* gWrt  = gWlt + 4096;    // [32][128]

    const int NB = (N + 1023) / 1024;          // scan tiles (20)
    const int EB = N / 32;                     // embedlin blocks (625)
    const int FBLK = (EA + 255) / 256;         // fill blocks
    const int GT = (N + 15) / 16;              // fused gather+linear tiles (1250)

    // ---- detect + zero deg/st ----
    k_detect_zero<<<64, 256, 0, stream>>>((const unsigned short*)d_in[0], flag, deg, N + 32);
    // ---- convert weights (+ f16 transposed) + degree count with rank capture
    k_convert<<<256, 256, 0, stream>>>(tab, wf, flag, dstArr, E, N, deg, rank,
                                       d_in[15], d_in[17], d_in[37], d_in[39],
                                       a2Wlt, a2Wrt, gWlt, gWrt);
    // ---- single-kernel lookback scan ----
    k_scanf<<<NB, 1024, 0, stream>>>(deg, offs, N, st, NB);
    // ---- CSR fill (rank trick) + fused embed+conv1-linear -> hxl1/fB1 ----
    k_fill_embedlin<<<EB + FBLK, 256, 0, stream>>>(srcArr, dstArr, E, N, offs, rank, csr,
                                                   d_in[0], flag, aeW, aeb,
                                                   a1Wl, a1bl, a1Wr, a1br, hxl1, fB1, EB);
    // ---- conv1 gather + conv2 linear (MFMA, fC stays in LDS) -> hxl2/fB2 ----
    k_gatlin<<<GT, 256, 0, stream>>>(hxl1, fB1, a1att, offs, csr, a1b,
                                     a2Wlt, a2bl, a2Wrt, a2br, hxl2, fB2, N);
    // ---- conv2 gather + global linear (MFMA) -> hxl1([N,32]) / fB1([N,32]) --
    k_gatling<<<GT, 256, 0, stream>>>(hxl2, fB2, a2att, offs, csr, a2b,
                                      gWlt, gbl, gWrt, gbr, hxl1, fB1, N);
    // ---- tail: global gather for the 64 focal dsts + head ----
    k_tailf<<<B, 64, 0, stream>>>(hxl1, fB1, gatt, offs, csr, gb, focal,
                                  clf, clW, clb, fcW, fcb, d_out, flag);
}

// Round 4
// 255.689 us; speedup vs baseline: 1.1199x; 1.0750x over previous
//
#include <hip/hip_runtime.h>
#include <hip/hip_bf16.h>
#include <hip/hip_fp16.h>
#include <math.h>

typedef __hip_bfloat16 bf16;
#define NEG_SLOPE 0.2f
#define SFLAG (1 << 30)

typedef _Float16 f16x8 __attribute__((ext_vector_type(8)));
typedef float f32x4 __attribute__((ext_vector_type(4)));

// ====== dtype detect (block 0) + zero deg/scan-state =========================
__global__ void k_detect_zero(const unsigned short* __restrict__ x, int* __restrict__ flag,
                              int* __restrict__ zbase, int n) {
    for (int i = blockIdx.x * blockDim.x + threadIdx.x; i < n; i += gridDim.x * blockDim.x)
        zbase[i] = 0;
    if (blockIdx.x == 0) {
        __shared__ int cnt;
        if (threadIdx.x == 0) cnt = 0;
        __syncthreads();
        int local = 0;
        for (int i = threadIdx.x; i < 2048; i += blockDim.x) {
            unsigned short w = x[2 * i];
            int e = (w >> 7) & 0xFF;
            if (e >= 0x90) local++;
        }
        atomicAdd(&cnt, local);
        __syncthreads();
        if (threadIdx.x == 0) flag[0] = (cnt > 100) ? 1 : 0;  // 1 => inputs are f32
    }
}

#define NSEG 25
struct Seg { const void* src; int n; int off; };
struct Tab { Seg s[NSEG]; };

__device__ __forceinline__ float ldconv(const void* src, int i, int f32mode) {
    return f32mode ? ((const float*)src)[i]
                   : __bfloat162float(((const bf16*)src)[i]);
}

// ====== convert weights fp32 + transposed f16 weights + degree/rank ==========
__global__ void k_convert(Tab tab, float* __restrict__ dst, const int* __restrict__ flag,
                          const int* __restrict__ dstArr, int E, int N,
                          int* __restrict__ deg, int* __restrict__ rank,
                          const void* a2WlS, const void* a2WrS,
                          const void* gWlS, const void* gWrS,
                          __half* __restrict__ a2Wlt, __half* __restrict__ a2Wrt,
                          __half* __restrict__ gWlt, __half* __restrict__ gWrt) {
    int f32mode = flag[0];
    int gid = blockIdx.x * blockDim.x + threadIdx.x;
    int gsz = gridDim.x * blockDim.x;
    for (int s = 0; s < NSEG; s++) {
        Seg sg = tab.s[s];
        for (int i = gid; i < sg.n; i += gsz) {
            dst[sg.off + i] = ldconv(sg.src, i, f32mode);
        }
    }
    // transposed f16 weights: Wt[j][k] = W[k][j]
    for (int i = gid; i < 128 * 128; i += gsz) {
        int k = i >> 7, j = i & 127;
        a2Wlt[(size_t)j * 128 + k] = __float2half(ldconv(a2WlS, i, f32mode));
        a2Wrt[(size_t)j * 128 + k] = __float2half(ldconv(a2WrS, i, f32mode));
    }
    for (int i = gid; i < 128 * 32; i += gsz) {
        int k = i >> 5, j = i & 31;
        gWlt[(size_t)j * 128 + k] = __float2half(ldconv(gWlS, i, f32mode));
        gWrt[(size_t)j * 128 + k] = __float2half(ldconv(gWrS, i, f32mode));
    }
    int EA = E + N;
    for (int e = gid; e < EA; e += gsz) {
        int d = (e < E) ? dstArr[e] : (e - E);
        rank[e] = atomicAdd(&deg[d], 1);
    }
}

// ====== single-kernel chained-lookback exclusive scan ========================
__launch_bounds__(1024)
__global__ void k_scanf(const int* __restrict__ deg, int* __restrict__ offs,
                        int n, int* __restrict__ st, int nb) {
    __shared__ int ws[16];
    __shared__ int stot, sprev;
    int tile = blockIdx.x;
    int i = tile * 1024 + threadIdx.x;
    int lane = threadIdx.x & 63, wid = threadIdx.x >> 6;
    int v = (i < n) ? deg[i] : 0;
    int x = v;
    #pragma unroll
    for (int o = 1; o < 64; o <<= 1) {
        int y = __shfl_up(x, o);
        if (lane >= o) x += y;
    }
    if (lane == 63) ws[wid] = x;
    __syncthreads();
    if (wid == 0) {
        int w = (lane < 16) ? ws[lane] : 0;
        int s = w;
        #pragma unroll
        for (int o = 1; o < 16; o <<= 1) {
            int y = __shfl_up(s, o);
            if (lane >= o) s += y;
        }
        if (lane < 16) ws[lane] = s - w;
        if (lane == 15) stot = s;
    }
    __syncthreads();
    int local = ws[wid] + x - v;     // block-local exclusive
    if (threadIdx.x == 0) {
        int prev = 0;
        if (tile > 0) {
            int vv;
            while ((((vv = __hip_atomic_load(&st[tile - 1], __ATOMIC_ACQUIRE,
                                             __HIP_MEMORY_SCOPE_AGENT))) & SFLAG) == 0) {}
            prev = vv & ~SFLAG;
        }
        __hip_atomic_store(&st[tile], (prev + stot) | SFLAG, __ATOMIC_RELEASE,
                           __HIP_MEMORY_SCOPE_AGENT);
        sprev = prev;
        if (tile == nb - 1) offs[n] = prev + stot;
    }
    __syncthreads();
    if (i < n) offs[i] = sprev + local;
}

// ====== fused: CSR fill via rank (blocks >= EB) + embed+conv1-linear =========
__launch_bounds__(256)
__global__ void k_fill_embedlin(const int* __restrict__ srcArr, const int* __restrict__ dstArr,
                                int E, int N, const int* __restrict__ offs,
                                const int* __restrict__ rank, int* __restrict__ csr,
                                const void* __restrict__ xraw, const int* __restrict__ flag,
                                const float* __restrict__ aeW, const float* __restrict__ aeb,
                                const float* __restrict__ Wl, const float* __restrict__ bl,
                                const float* __restrict__ Wr, const float* __restrict__ br,
                                __half* __restrict__ outl, float* __restrict__ outr,
                                int EB) {
    __shared__ float xs[100 * 36];
    __shared__ float axs[32 * 36];
    if (blockIdx.x >= EB) {
        int e = (blockIdx.x - EB) * 256 + threadIdx.x;
        int EA = E + N;
        if (e >= EA) return;
        int d, s;
        if (e < E) { d = dstArr[e]; s = srcArr[e]; } else { d = s = e - E; }
        csr[offs[d] + rank[e]] = s;     // no atomics: rank captured during count
        return;
    }
    constexpr int NTP = 36;
    int t = threadIdx.x, nb = blockIdx.x * 32;
    if (flag[0]) {
        const float4* x4 = (const float4*)xraw;
        for (int idx = t; idx < 32 * 25; idx += 256) {
            int node = idx / 25, k4 = idx % 25;
            float4 v = x4[(size_t)(nb + node) * 25 + k4];
            xs[(k4 * 4 + 0) * NTP + node] = v.x;
            xs[(k4 * 4 + 1) * NTP + node] = v.y;
            xs[(k4 * 4 + 2) * NTP + node] = v.z;
            xs[(k4 * 4 + 3) * NTP + node] = v.w;
        }
    } else {
        const ushort4* xu = (const ushort4*)xraw;
        for (int idx = t; idx < 32 * 25; idx += 256) {
            int node = idx / 25, k4 = idx % 25;
            ushort4 u = xu[(size_t)(nb + node) * 25 + k4];
            xs[(k4 * 4 + 0) * NTP + node] = __uint_as_float((unsigned)u.x << 16);
            xs[(k4 * 4 + 1) * NTP + node] = __uint_as_float((unsigned)u.y << 16);
            xs[(k4 * 4 + 2) * NTP + node] = __uint_as_float((unsigned)u.z << 16);
            xs[(k4 * 4 + 3) * NTP + node] = __uint_as_float((unsigned)u.w << 16);
        }
    }
    __syncthreads();
    {
        int j = t & 31, g0 = t >> 5;
        float a0 = 0.f, a1 = 0.f, a2 = 0.f, a3 = 0.f;
        #pragma unroll 10
        for (int k = 0; k < 100; k++) {
            float w = aeW[k * 32 + j];
            const float4 xv = *(const float4*)&xs[k * NTP + g0 * 4];
            a0 += w * xv.x; a1 += w * xv.y; a2 += w * xv.z; a3 += w * xv.w;
        }
        float bj = aeb[j];
        axs[j * NTP + g0 * 4 + 0] = fmaxf(a0 + bj, 0.f);
        axs[j * NTP + g0 * 4 + 1] = fmaxf(a1 + bj, 0.f);
        axs[j * NTP + g0 * 4 + 2] = fmaxf(a2 + bj, 0.f);
        axs[j * NTP + g0 * 4 + 3] = fmaxf(a3 + bj, 0.f);
    }
    __syncthreads();
    {
        int j = t & 63, g0 = t >> 6;
        float aL0[2][4], aL1[2][4], aR0[2][4], aR1[2][4];
        #pragma unroll
        for (int g = 0; g < 2; g++)
            #pragma unroll
            for (int c = 0; c < 4; c++) { aL0[g][c]=0.f; aL1[g][c]=0.f; aR0[g][c]=0.f; aR1[g][c]=0.f; }
        #pragma unroll 4
        for (int k = 0; k < 32; k++) {
            float wl0 = Wl[k * 128 + j];
            float wl1 = Wl[k * 128 + j + 64];
            float wr0 = Wr[k * 128 + j];
            float wr1 = Wr[k * 128 + j + 64];
            #pragma unroll
            for (int g = 0; g < 2; g++) {
                const float4 xv = *(const float4*)&axs[k * NTP + (g0 + g * 4) * 4];
                aL0[g][0] += wl0 * xv.x; aL0[g][1] += wl0 * xv.y; aL0[g][2] += wl0 * xv.z; aL0[g][3] += wl0 * xv.w;
                aL1[g][0] += wl1 * xv.x; aL1[g][1] += wl1 * xv.y; aL1[g][2] += wl1 * xv.z; aL1[g][3] += wl1 * xv.w;
                aR0[g][0] += wr0 * xv.x; aR0[g][1] += wr0 * xv.y; aR0[g][2] += wr0 * xv.z; aR0[g][3] += wr0 * xv.w;
                aR1[g][0] += wr1 * xv.x; aR1[g][1] += wr1 * xv.y; aR1[g][2] += wr1 * xv.z; aR1[g][3] += wr1 * xv.w;
            }
        }
        float bl0 = bl[j], bl1 = bl[j + 64], br0 = br[j], br1 = br[j + 64];
        #pragma unroll
        for (int g = 0; g < 2; g++) {
            int n0 = nb + (g0 + g * 4) * 4;
            #pragma unroll
            for (int c = 0; c < 4; c++) {
                size_t row = (size_t)(n0 + c) * 128;
                outl[row + j]      = __float2half(aL0[g][c] + bl0);
                outl[row + j + 64] = __float2half(aL1[g][c] + bl1);
                outr[row + j]      = aR0[g][c] + br0;
                outr[row + j + 64] = aR1[g][c] + br1;
            }
        }
    }
}

// ====== per-edge math (16-lane group, 8 channels/lane) =======================
__device__ __forceinline__ void gat_proc(float4 raw, bool valid,
                                         const float* xrd, const float* av,
                                         float* acc, float& sm) {
    const __half2* h = (const __half2*)&raw;
    float v[8];
    float2 f;
    f = __half22float2(h[0]); v[0] = f.x; v[1] = f.y;
    f = __half22float2(h[1]); v[2] = f.x; v[3] = f.y;
    f = __half22float2(h[2]); v[4] = f.x; v[5] = f.y;
    f = __half22float2(h[3]); v[6] = f.x; v[7] = f.y;
    float p = 0.f;
    #pragma unroll
    for (int c = 0; c < 8; c++) {
        float u = v[c] + xrd[c];
        u = (u > 0.f) ? u : NEG_SLOPE * u;
        p += u * av[c];
    }
    p += __shfl_xor(p, 1);
    p += __shfl_xor(p, 2);
    p += __shfl_xor(p, 4);
    p += __shfl_xor(p, 8);
    float w = __expf(fminf(p, 80.f));
    if (!valid) w = 0.f;
    sm += w;
    #pragma unroll
    for (int c = 0; c < 8; c++) acc[c] += w * v[c];
}

// ====== GAT H=4 gather of ONE dst per 16-lane group into LDS row `node` =====
// Round-1 verified structure: chunked csr (16 at a time, prefetch next), 4
// xl-row loads in flight per group. d < 0 => inactive group (zeros written).
// xsh layout: xsh[node * 136 + ch], node in [0,16), ch in [0,128). 4.35 KB.
__device__ __forceinline__ void gat16_to_lds(__half* xsh,
                                             const __half* __restrict__ xl,
                                             const float* __restrict__ xr,
                                             const float* __restrict__ att,
                                             const int* __restrict__ offs,
                                             const int* __restrict__ csr,
                                             const float* __restrict__ bias,
                                             int d, int node) {
    int t = threadIdx.x;
    int lane = t & 63;
    int sub = lane & 15;                      // lane within group
    int lb = lane & 48;                       // group base lane
    float av[8];
    {
        const float4* t4 = (const float4*)(att + sub * 8);
        float4 c = t4[0], e = t4[1];
        av[0]=c.x; av[1]=c.y; av[2]=c.z; av[3]=c.w;
        av[4]=e.x; av[5]=e.y; av[6]=e.z; av[7]=e.w;
    }
    bool ok = d >= 0;
    int i0 = ok ? offs[d] : 0;
    int i1 = ok ? offs[d + 1] : 0;
    int cnt = i1 - i0;

    float xrd[8];
    #pragma unroll
    for (int c = 0; c < 8; c++) xrd[c] = 0.f;
    if (ok) {
        const float4* p4 = (const float4*)(xr + (size_t)d * 128 + sub * 8);
        float4 a = p4[0], b = p4[1];
        xrd[0]=a.x; xrd[1]=a.y; xrd[2]=a.z; xrd[3]=a.w;
        xrd[4]=b.x; xrd[5]=b.y; xrd[6]=b.z; xrd[7]=b.w;
    }
    float acc[8];
    #pragma unroll
    for (int c = 0; c < 8; c++) acc[c] = 0.f;
    float sm = 0.f;

    // first csr chunk (16 edges, one coalesced 64B load per group)
    int myv = (sub < cnt) ? csr[i0 + sub] : 0;
    for (int c0 = 0; c0 < cnt; c0 += 16) {
        // prefetch next chunk's indices while processing current
        int myv_nxt = (c0 + 16 + sub < cnt) ? csr[i0 + c0 + 16 + sub] : 0;
        int rem = min(cnt - c0, 16);
        for (int k = 0; k < rem; k += 4) {
            int s0 = __shfl(myv, lb + k + 0);
            int s1 = __shfl(myv, lb + k + 1);
            int s2 = __shfl(myv, lb + k + 2);
            int s3 = __shfl(myv, lb + k + 3);
            float4 r0 = *(const float4*)(xl + (size_t)s0 * 128 + sub * 8);
            float4 r1 = *(const float4*)(xl + (size_t)s1 * 128 + sub * 8);
            float4 r2 = *(const float4*)(xl + (size_t)s2 * 128 + sub * 8);
            float4 r3 = *(const float4*)(xl + (size_t)s3 * 128 + sub * 8);
            gat_proc(r0, true,        xrd, av, acc, sm);
            gat_proc(r1, k + 1 < rem, xrd, av, acc, sm);
            gat_proc(r2, k + 2 < rem, xrd, av, acc, sm);
            gat_proc(r3, k + 3 < rem, xrd, av, acc, sm);
        }
        myv = myv_nxt;
    }

    // acc is already the full per-dst sum (group's 16 lanes cover 128 ch)
    int ch = sub * 8;
    if (ok) {
        float inv = 1.f / (sm + 1e-16f);
        #pragma unroll
        for (int c = 0; c < 8; c += 2) {
            __half2 hv;
            hv.x = __float2half(fmaxf(acc[c]     * inv + bias[ch + c],     0.f));
            hv.y = __float2half(fmaxf(acc[c + 1] * inv + bias[ch + c + 1], 0.f));
            *(__half2*)&xsh[node * 136 + ch + c] = hv;
        }
    } else {
        // keep MFMA inputs clean for unused rows
        #pragma unroll
        for (int c = 0; c < 8; c += 2)
            *(__half2*)&xsh[node * 136 + ch + c] = __half2{__half(0.f), __half(0.f)};
    }
}

// ====== fused: conv1 gather (16-dst tile) -> conv2 dual linear via MFMA ======
// Extra block (blockIdx == GT) builds the focal-neighborhood dst list L for
// the sparse global-GAT stage (k_gatling): L = concat of focal csr ranges.
__launch_bounds__(256)
__global__ void k_gatlin(const __half* __restrict__ xl, const float* __restrict__ xr,
                         const float* __restrict__ att,
                         const int* __restrict__ offs, const int* __restrict__ csr,
                         const float* __restrict__ bias,
                         const __half* __restrict__ Wlt, const float* __restrict__ bl,
                         const __half* __restrict__ Wrt, const float* __restrict__ br,
                         __half* __restrict__ outl, float* __restrict__ outr, int N,
                         const int* __restrict__ focal, int B,
                         int* __restrict__ L, int* __restrict__ Lcnt, int GT) {
    if (blockIdx.x >= GT) {
        int t = threadIdx.x;
        if (t < B) {
            int f = focal[t];
            int j0 = offs[f], j1 = offs[f + 1];
            int base = atomicAdd(Lcnt, j1 - j0);
            for (int j = j0; j < j1; j++) L[base + (j - j0)] = csr[j];
        }
        return;
    }
    __shared__ __align__(16) __half xsh[16 * 136];
    int nb = blockIdx.x * 16;
    int t = threadIdx.x;
    int lane = t & 63, wv = t >> 6;
    int quad = lane >> 4, n16 = lane & 15;
    {
        int node = wv * 4 + quad;
        int dd = nb + node;
        gat16_to_lds(xsh, xl, xr, att, offs, csr, bias, (dd < N) ? dd : -1, node);
    }
    __syncthreads();

    // A fragments: A[m=lane&15][k=quad*8+i], 4 k-tiles of 32
    f16x8 a[4];
    #pragma unroll
    for (int kt = 0; kt < 4; kt++)
        a[kt] = *(const f16x8*)&xsh[n16 * 136 + kt * 32 + quad * 8];

    int j0 = wv * 32;   // this wave's 32 output columns (two 16-tiles), for L and R
    f32x4 aL0 = {0.f,0.f,0.f,0.f}, aL1 = {0.f,0.f,0.f,0.f};
    f32x4 aR0 = {0.f,0.f,0.f,0.f}, aR1 = {0.f,0.f,0.f,0.f};
    #pragma unroll
    for (int kt = 0; kt < 4; kt++) {
        int ko = kt * 32 + quad * 8;
        f16x8 b0 = *(const f16x8*)&Wlt[(size_t)(j0 + n16) * 128 + ko];
        f16x8 b1 = *(const f16x8*)&Wlt[(size_t)(j0 + 16 + n16) * 128 + ko];
        f16x8 b2 = *(const f16x8*)&Wrt[(size_t)(j0 + n16) * 128 + ko];
        f16x8 b3 = *(const f16x8*)&Wrt[(size_t)(j0 + 16 + n16) * 128 + ko];
        aL0 = __builtin_amdgcn_mfma_f32_16x16x32_f16(a[kt], b0, aL0, 0, 0, 0);
        aL1 = __builtin_amdgcn_mfma_f32_16x16x32_f16(a[kt], b1, aL1, 0, 0, 0);
        aR0 = __builtin_amdgcn_mfma_f32_16x16x32_f16(a[kt], b2, aR0, 0, 0, 0);
        aR1 = __builtin_amdgcn_mfma_f32_16x16x32_f16(a[kt], b3, aR1, 0, 0, 0);
    }
    float blj0 = bl[j0 + n16], blj1 = bl[j0 + 16 + n16];
    float brj0 = br[j0 + n16], brj1 = br[j0 + 16 + n16];
    #pragma unroll
    for (int r = 0; r < 4; r++) {
        int node = quad * 4 + r;        // D row = node
        if (nb + node >= N) continue;
        size_t row = (size_t)(nb + node) * 128;
        outl[row + j0 + n16]      = __float2half(aL0[r] + blj0);
        outl[row + j0 + 16 + n16] = __float2half(aL1[r] + blj1);
        outr[row + j0 + n16]      = aR0[r] + brj0;
        outr[row + j0 + 16 + n16] = aR1[r] + brj1;
    }
}

// ====== sparse: conv2 gather + global linear ONLY at focal-needed dsts =======
// global_features is consumed only at focal nodes; the global-GAT there reads
// xl_g at csr-sources of focal edges and xr_g at focal (in L via self-loops).
// So conv2-gather+global-linear runs over L (~B*deg ~= 1100 dsts), not N.
__launch_bounds__(256)
__global__ void k_gatling(const __half* __restrict__ xl, const float* __restrict__ xr,
                          const float* __restrict__ att,
                          const int* __restrict__ offs, const int* __restrict__ csr,
                          const float* __restrict__ bias,
                          const __half* __restrict__ Wlt, const float* __restrict__ bl,
                          const __half* __restrict__ Wrt, const float* __restrict__ br,
                          __half* __restrict__ outl, float* __restrict__ outr,
                          const int* __restrict__ L, const int* __restrict__ Lcnt) {
    __shared__ __align__(16) __half xsh[16 * 136];
    int total = *Lcnt;
    int t = threadIdx.x;
    int lane = t & 63, wv = t >> 6;
    int quad = lane >> 4, n16 = lane & 15;

    for (int tile = blockIdx.x; tile * 16 < total; tile += gridDim.x) {
        if (tile != (int)blockIdx.x) __syncthreads();   // xsh reuse guard
        int node = wv * 4 + quad;
        int idx = tile * 16 + node;
        int d = (idx < total) ? L[idx] : -1;
        gat16_to_lds(xsh, xl, xr, att, offs, csr, bias, d, node);
        __syncthreads();

        f16x8 a[4];
        #pragma unroll
        for (int kt = 0; kt < 4; kt++)
            a[kt] = *(const f16x8*)&xsh[n16 * 136 + kt * 32 + quad * 8];

        // wave -> one 16x16 tile: wv 0: L j0=0; 1: L j0=16; 2: R j0=0; 3: R j0=16
        const __half* Wt = (wv < 2) ? Wlt : Wrt;
        int j0 = (wv & 1) * 16;
        f32x4 accv = {0.f,0.f,0.f,0.f};
        #pragma unroll
        for (int kt = 0; kt < 4; kt++) {
            f16x8 b = *(const f16x8*)&Wt[(size_t)(j0 + n16) * 128 + kt * 32 + quad * 8];
            accv = __builtin_amdgcn_mfma_f32_16x16x32_f16(a[kt], b, accv, 0, 0, 0);
        }
        float bj = ((wv < 2) ? bl : br)[j0 + n16];
        #pragma unroll
        for (int r = 0; r < 4; r++) {
            int nn = quad * 4 + r;
            int gidx = tile * 16 + nn;
            if (gidx >= total) continue;
            int gd = L[gidx];              // duplicates write identical values
            size_t row = (size_t)gd * 32;
            if (wv < 2) outl[row + j0 + n16] = __float2half(accv[r] + bj);
            else        outr[row + j0 + n16] = accv[r] + bj;
        }
    }
}

// ===== tail: global-GAT gather for the 64 FOCAL dsts only + output head =====
__launch_bounds__(64)
__global__ void k_tailf(const __half* __restrict__ xl, const float* __restrict__ xr,
                        const float* __restrict__ att,
                        const int* __restrict__ offs, const int* __restrict__ csr,
                        const float* __restrict__ gb, const int* __restrict__ focal,
                        const float* __restrict__ clf, const float* __restrict__ clW,
                        const float* __restrict__ clb, const float* __restrict__ fcW,
                        const float* __restrict__ fcb, void* __restrict__ out,
                        const int* __restrict__ flag) {
    __shared__ float comb[64];
    __shared__ float ssb[2];
    int b = blockIdx.x;
    int t = threadIdx.x;                  // 64
    int d = focal[b];
    int grp = t >> 3, sub = t & 7;        // 8 edge-groups x 8 lanes (4 ch each)
    int i0 = offs[d], i1 = offs[d + 1];

    float xrd[4], av[4], acc[4];
    {
        float4 a = *(const float4*)(xr + (size_t)d * 32 + sub * 4);
        xrd[0]=a.x; xrd[1]=a.y; xrd[2]=a.z; xrd[3]=a.w;
        float4 c = *(const float4*)(att + sub * 4);
        av[0]=c.x; av[1]=c.y; av[2]=c.z; av[3]=c.w;
    }
    #pragma unroll
    for (int c = 0; c < 4; c++) acc[c] = 0.f;
    float sm = 0.f;

    for (int i = i0 + grp; i < i1; i += 8) {
        float2 raw = *(const float2*)(xl + (size_t)csr[i] * 32 + sub * 4);
        const __half2* h = (const __half2*)&raw;
        float v[4];
        float2 f;
        f = __half22float2(h[0]); v[0] = f.x; v[1] = f.y;
        f = __half22float2(h[1]); v[2] = f.x; v[3] = f.y;
        float p = 0.f;
        #pragma unroll
        for (int c = 0; c < 4; c++) {
            float u = v[c] + xrd[c];
            u = (u > 0.f) ? u : NEG_SLOPE * u;
            p += u * av[c];
        }
        p += __shfl_xor(p, 1);
        p += __shfl_xor(p, 2);
        p += __shfl_xor(p, 4);
        float w = __expf(fminf(p, 80.f));
        sm += w;
        #pragma unroll
        for (int c = 0; c < 4; c++) acc[c] += w * v[c];
    }
    // merge 8 edge-groups
    sm += __shfl_xor(sm, 8); sm += __shfl_xor(sm, 16); sm += __shfl_xor(sm, 32);
    #pragma unroll
    for (int c = 0; c < 4; c++) {
        acc[c] += __shfl_xor(acc[c], 8);
        acc[c] += __shfl_xor(acc[c], 16);
        acc[c] += __shfl_xor(acc[c], 32);
    }
    if (grp == 0) {
        float inv = 1.f / (sm + 1e-16f);
        #pragma unroll
        for (int c = 0; c < 4; c++)
            comb[sub * 4 + c] = fmaxf(acc[c] * inv + gb[sub * 4 + c], 0.f);
    }
    if (t < 2) {
        float s = 0.f;
        for (int l = 0; l < 50; l++) s += clf[(size_t)b * 100 + l * 2 + t];
        ssb[t] = s / 50.f;
    }
    __syncthreads();
    if (t < 32) comb[32 + t] = ssb[0] * clW[t] + ssb[1] * clW[32 + t] + clb[t];
    __syncthreads();
    if (t < 60) {
        float a2 = fcb[t];
        #pragma unroll 16
        for (int k = 0; k < 64; k++) a2 += comb[k] * fcW[k * 60 + t];
        if (flag[0]) ((float*)out)[b * 60 + t] = a2;
        else ((bf16*)out)[b * 60 + t] = __float2bfloat16(a2);
    }
}

extern "C" void kernel_launch(void* const* d_in, const int* in_sizes, int n_in,
                              void* d_out, int out_size, void* d_ws, size_t ws_size,
                              hipStream_t stream) {
    const int* edge  = (const int*)d_in[1];
    const int* focal = (const int*)d_in[5];

    const int N = in_sizes[0] / 100;   // 20000
    const int E = in_sizes[1] / 2;     // 320000
    const int B = in_sizes[5];         // 64
    const int EA = E + N;
    const int* srcArr = edge;
    const int* dstArr = edge + E;

    // ---- conversion table: weights + centerlines -> fp32 in ws (x stays raw)
    const int idxs[NSEG] = {7,8,9,10,11,12,13,14,15,16,17,18,19,20,
                            35,36,37,38,39,40,41,42,43,44, 6};
    float* base = (float*)d_ws;
    int* flag = (int*)base;            // base[0..15] reserved
    float* wf = base + 16;
    Tab tab;
    int off[NSEG];
    int o = 0;
    for (int i = 0; i < NSEG; i++) {
        tab.s[i].src = d_in[idxs[i]];
        tab.s[i].n   = in_sizes[idxs[i]];
        tab.s[i].off = o;
        off[i] = o;
        o += in_sizes[idxs[i]];
    }
    const float* aeW  = wf + off[0],  *aeb  = wf + off[1];
    const float* a1Wl = wf + off[2],  *a1bl = wf + off[3];
    const float* a1Wr = wf + off[4],  *a1br = wf + off[5];
    const float* a1att= wf + off[6],  *a1b  = wf + off[7];
    const float* a2bl = wf + off[9];
    const float* a2br = wf + off[11];
    const float* a2att= wf + off[12], *a2b  = wf + off[13];
    const float* clW  = wf + off[14], *clb  = wf + off[15];
    const float* gbl  = wf + off[17];
    const float* gbr  = wf + off[19];
    const float* gatt = wf + off[20], *gb   = wf + off[21];
    const float* fcW  = wf + off[22], *fcb  = wf + off[23];
    const float* clf  = wf + off[24];

    // ---- remaining workspace (keep 16B alignment) ----
    float* p = wf + o + ((4 - (o & 3)) & 3);
    size_t N128 = (size_t)N * 128;
    __half* hxl1 = (__half*)p;      p += (size_t)N * 64;    // conv1 xl fp16 [N,128]; later global xl [N,32]
    float* fB1  = p;                p += N128;              // conv1 xr fp32; later global xrg [N,32]
    __half* hxl2 = (__half*)p;      p += (size_t)N * 64;    // conv2 xl fp16 [N,128]
    float* fB2  = p;                p += N128;              // conv2 xr fp32
    int* deg    = (int*)p;          // [N]
    int* st     = deg + N;          // [32] scan lookback state (NB<=30 used); st[30] = Lcnt
    int* offs   = st + 32;          // N+1
    int* rank   = offs + N + 1;     // EA
    int* csr    = rank + EA;        // EA (src node ids)
    // transposed f16 weights (16B aligned)
    uintptr_t up = (uintptr_t)(csr + EA);
    up = (up + 15) & ~(uintptr_t)15;
    __half* a2Wlt = (__half*)up;    // [128][128]
    __half* a2Wrt = a2Wlt + 16384;  // [128][128]
    __half* gWlt  = a2Wrt + 16384;  // [32][128]
    __half* gWrt  = gWlt + 4096;    // [32][128]
    int* Lbuf = (int*)(gWrt + 4096);   // focal-neighborhood dst list (<= EA)
    int* Lcnt = st + 30;               // zeroed by k_detect_zero (in deg..st range)

    const int NB = (N + 1023) / 1024;          // scan tiles (20)
    const int EB = N / 32;                     // embedlin blocks (625)
    const int FBLK = (EA + 255) / 256;         // fill blocks
    const int GT = (N + 15) / 16;              // fused gather+linear tiles (1250)

    // ---- detect + zero deg/st (incl. Lcnt) ----
    k_detect_zero<<<64, 256, 0, stream>>>((const unsigned short*)d_in[0], flag, deg, N + 32);
    // ---- convert weights (+ f16 transposed) + degree count with rank capture
    k_convert<<<256, 256, 0, stream>>>(tab, wf, flag, dstArr, E, N, deg, rank,
                                       d_in[15], d_in[17], d_in[37], d_in[39],
                                       a2Wlt, a2Wrt, gWlt, gWrt);
    // ---- single-kernel lookback scan ----
    k_scanf<<<NB, 1024, 0, stream>>>(deg, offs, N, st, NB);
    // ---- CSR fill (rank trick) + fused embed+conv1-linear -> hxl1/fB1 ----
    k_fill_embedlin<<<EB + FBLK, 256, 0, stream>>>(srcArr, dstArr, E, N, offs, rank, csr,
                                                   d_in[0], flag, aeW, aeb,
                                                   a1Wl, a1bl, a1Wr, a1br, hxl1, fB1, EB);
    // ---- conv1 gather + conv2 linear (MFMA) -> hxl2/fB2; +1 block builds L --
    k_gatlin<<<GT + 1, 256, 0, stream>>>(hxl1, fB1, a1att, offs, csr, a1b,
                                         a2Wlt, a2bl, a2Wrt, a2br, hxl2, fB2, N,
                                         focal, B, Lbuf, Lcnt, GT);
    // ---- SPARSE conv2 gather + global linear over L only -> hxl1/fB1 -------
    k_gatling<<<128, 256, 0, stream>>>(hxl2, fB2, a2att, offs, csr, a2b,
                                       gWlt, gbl, gWrt, gbr, hxl1, fB1, Lbuf, Lcnt);
    // ---- tail: global gather for the 64 focal dsts + head ----
    k_tailf<<<B, 64, 0, stream>>>(hxl1, fB1, gatt, offs, csr, gb, focal,
                                  clf, clW, clb, fcW, fcb, d_out, flag);
}